// Round 1
// baseline (1029.071 us; speedup 1.0000x reference)
//
#include <hip/hip_runtime.h>
#include <hip/hip_bf16.h>
#include <cstdint>
#include <cstddef>

#define B_    512
#define HW_   196
#define ENC_  2048
#define DEC_  512
#define ATTN_ 512
#define M_    (B_*HW_)   // 100352

typedef __attribute__((ext_vector_type(8))) short short8;
typedef __attribute__((ext_vector_type(4))) float f32x4;

__device__ __forceinline__ unsigned short f2bf(float x) {
  union { float f; unsigned int u; } c; c.f = x;
  unsigned int u = c.u;
  unsigned int r = (u + 0x7FFFu + ((u >> 16) & 1u)) >> 16;  // RNE
  return (unsigned short)r;
}

// ---------------- kernel 1: attn2p[b][a] = dec_h[b]·W_dec[:,a] + b_dec[a] + b_enc[a]
__global__ __launch_bounds__(256)
void k_attn2(const float* __restrict__ dec_h, const float* __restrict__ Wdec,
             const float* __restrict__ bdec, const float* __restrict__ benc,
             float* __restrict__ attn2p) {
  __shared__ float dh[DEC_];
  const int b = blockIdx.x;
  const int t = threadIdx.x;
  dh[t]       = dec_h[b*DEC_ + t];
  dh[t + 256] = dec_h[b*DEC_ + t + 256];
  __syncthreads();
  #pragma unroll
  for (int rep = 0; rep < 2; ++rep) {
    const int a = t + rep*256;
    float acc = bdec[a] + benc[a];
    #pragma unroll 8
    for (int k = 0; k < DEC_; ++k)
      acc = fmaf(dh[k], Wdec[(size_t)k*ATTN_ + a], acc);
    attn2p[(size_t)b*ATTN_ + a] = acc;
  }
}

// ---------------- kernel 2: W_encT[a][e] = bf16(W_enc[e][a])
__global__ __launch_bounds__(256)
void k_transpose(const float* __restrict__ Wenc, unsigned short* __restrict__ WencT) {
  __shared__ float tile[32][33];
  const int e0 = blockIdx.x * 32;
  const int a0 = blockIdx.y * 32;
  const int t  = threadIdx.x;
  const int li = t >> 5;   // 0..7
  const int lj = t & 31;
  #pragma unroll
  for (int rep = 0; rep < 4; ++rep) {
    const int i = li + rep*8;
    tile[i][lj] = Wenc[(size_t)(e0 + i)*ATTN_ + a0 + lj];
  }
  __syncthreads();
  #pragma unroll
  for (int rep = 0; rep < 4; ++rep) {
    const int ar = li + rep*8;
    WencT[(size_t)(a0 + ar)*ENC_ + e0 + lj] = f2bf(tile[lj][ar]);
  }
}

// ---------------- kernel 3: fused GEMM + bias + relu + dot(W_v) -> partial logits
// tile: BM=128 rows (m = b*196+s), BN=128 cols (attn dim), K=2048, BK=32
// grid: 3136 blocks = 784 m-tiles x 4 n-blocks, swizzled so the 4 n-siblings
// of one m-tile land on the same XCD (share the A-tile via L2).
#define BM 128
#define BN 128
#define BK 32
#define LDK 40   // padded k-stride (bf16 elems): 80B rows, 16B-aligned, 2-way banks

__global__ __launch_bounds__(256, 2)
void k_gemm_logits(const float* __restrict__ enc,
                   const unsigned short* __restrict__ WencT,
                   const float* __restrict__ attn2p,
                   const float* __restrict__ Wv,
                   float* __restrict__ partials) {
  __shared__ unsigned short As[BM*LDK];
  __shared__ unsigned short Bs[BN*LDK];
  __shared__ float plog[BM][2];

  const int tid  = threadIdx.x;
  const int id   = blockIdx.x;
  const int xcd  = id & 7;
  const int rest = id >> 3;
  const int nb   = rest & 3;
  const int mblk = (rest >> 2) * 8 + xcd;   // 784 = 98*8, bijective
  const int r0 = mblk * BM;
  const int n0 = nb * BN;

  // staging: 2 threads per row, 16 k-elems each
  const int srow = tid >> 1;
  const int skh  = (tid & 1) << 4;
  const float*          aptr = enc   + (size_t)(r0 + srow)*ENC_ + skh;
  const unsigned short* bptr = WencT + (size_t)(n0 + srow)*ENC_ + skh;

  const int w  = tid >> 6;
  const int l  = tid & 63;
  const int wm = w >> 1, wn = w & 1;
  const int lrow = l & 15;
  const int lk   = (l >> 4) << 3;
  const int g4   = (l >> 4) << 2;

  f32x4 acc[4][4];
  #pragma unroll
  for (int mi = 0; mi < 4; ++mi)
    #pragma unroll
    for (int ni = 0; ni < 4; ++ni)
      acc[mi][ni] = (f32x4){0.f, 0.f, 0.f, 0.f};

  float4 arg[4];
  uint4  brg[2];
  {
    const float4* ap = reinterpret_cast<const float4*>(aptr);
    arg[0] = ap[0]; arg[1] = ap[1]; arg[2] = ap[2]; arg[3] = ap[3];
    const uint4* bp = reinterpret_cast<const uint4*>(bptr);
    brg[0] = bp[0]; brg[1] = bp[1];
  }

  const int NT = ENC_ / BK;  // 64
  for (int kt = 0; kt < NT; ++kt) {
    if (kt) __syncthreads();
    {
      unsigned int pk[8];
      #pragma unroll
      for (int i = 0; i < 4; ++i) {
        pk[2*i]   = (unsigned)f2bf(arg[i].x) | ((unsigned)f2bf(arg[i].y) << 16);
        pk[2*i+1] = (unsigned)f2bf(arg[i].z) | ((unsigned)f2bf(arg[i].w) << 16);
      }
      uint4* da = reinterpret_cast<uint4*>(&As[srow*LDK + skh]);
      da[0] = make_uint4(pk[0], pk[1], pk[2], pk[3]);
      da[1] = make_uint4(pk[4], pk[5], pk[6], pk[7]);
      uint4* db = reinterpret_cast<uint4*>(&Bs[srow*LDK + skh]);
      db[0] = brg[0];
      db[1] = brg[1];
    }
    __syncthreads();
    if (kt + 1 < NT) {  // issue next-tile loads; HBM latency hides under MFMA
      const int k0 = (kt + 1) * BK;
      const float4* ap = reinterpret_cast<const float4*>(aptr + k0);
      arg[0] = ap[0]; arg[1] = ap[1]; arg[2] = ap[2]; arg[3] = ap[3];
      const uint4* bp = reinterpret_cast<const uint4*>(bptr + k0);
      brg[0] = bp[0]; brg[1] = bp[1];
    }
    short8 aF[4], bF[4];
    #pragma unroll
    for (int mi = 0; mi < 4; ++mi)
      aF[mi] = *reinterpret_cast<const short8*>(&As[(wm*64 + mi*16 + lrow)*LDK + lk]);
    #pragma unroll
    for (int ni = 0; ni < 4; ++ni)
      bF[ni] = *reinterpret_cast<const short8*>(&Bs[(wn*64 + ni*16 + lrow)*LDK + lk]);
    #pragma unroll
    for (int mi = 0; mi < 4; ++mi)
      #pragma unroll
      for (int ni = 0; ni < 4; ++ni)
        acc[mi][ni] = __builtin_amdgcn_mfma_f32_16x16x32_bf16(aF[mi], bF[ni], acc[mi][ni], 0, 0, 0);
  }
  __syncthreads();

  // epilogue: relu(acc + attn2p) · W_v, reduced over this block's 128 cols
  float wvv[4];
  #pragma unroll
  for (int ni = 0; ni < 4; ++ni) wvv[ni] = Wv[n0 + wn*64 + ni*16 + lrow];
  #pragma unroll
  for (int mi = 0; mi < 4; ++mi) {
    #pragma unroll
    for (int j = 0; j < 4; ++j) {
      const int row_local = wm*64 + mi*16 + g4 + j;
      const int r  = r0 + row_local;
      const int bb = r / HW_;
      const float* a2 = attn2p + (size_t)bb*ATTN_ + n0 + wn*64;
      float s = 0.f;
      #pragma unroll
      for (int ni = 0; ni < 4; ++ni) {
        float v = acc[mi][ni][j] + a2[ni*16 + lrow];
        v = fmaxf(v, 0.f);
        s = fmaf(v, wvv[ni], s);
      }
      s += __shfl_xor(s, 1);
      s += __shfl_xor(s, 2);
      s += __shfl_xor(s, 4);
      s += __shfl_xor(s, 8);
      if (lrow == 0) plog[row_local][wn] = s;
    }
  }
  __syncthreads();
  if (tid < BM)
    partials[(size_t)(r0 + tid)*4 + nb] = plog[tid][0] + plog[tid][1];
}

// ---------------- kernel 4: softmax over s (196) per b; alpha -> d_out tail
__global__ __launch_bounds__(64)
void k_softmax(const float* __restrict__ partials, const float* __restrict__ bvp,
               float* __restrict__ alpha) {
  const int b = blockIdx.x;
  const int t = threadIdx.x;
  const float bv = bvp[0];
  float lg[4];
  #pragma unroll
  for (int i = 0; i < 4; ++i) {
    const int s = t + i*64;
    if (s < HW_) {
      const float4 p = *reinterpret_cast<const float4*>(&partials[(size_t)(b*HW_ + s)*4]);
      lg[i] = p.x + p.y + p.z + p.w + bv;
    } else lg[i] = -INFINITY;
  }
  float mx = fmaxf(fmaxf(lg[0], lg[1]), fmaxf(lg[2], lg[3]));
  #pragma unroll
  for (int off = 32; off; off >>= 1) mx = fmaxf(mx, __shfl_xor(mx, off));
  float sum = 0.f;
  #pragma unroll
  for (int i = 0; i < 4; ++i) { lg[i] = expf(lg[i] - mx); sum += lg[i]; }
  #pragma unroll
  for (int off = 32; off; off >>= 1) sum += __shfl_xor(sum, off);
  const float inv = 1.0f / sum;
  #pragma unroll
  for (int i = 0; i < 4; ++i) {
    const int s = t + i*64;
    if (s < HW_) alpha[b*HW_ + s] = lg[i] * inv;
  }
}

// ---------------- kernel 5: context[b][e] = sum_s alpha[b][s] * enc[b][s][e]
__global__ __launch_bounds__(256)
void k_context(const float* __restrict__ enc, const float* __restrict__ alpha,
               float* __restrict__ ctx) {
  __shared__ float al[HW_];
  const int bi = blockIdx.x;
  const int b  = bi >> 1;
  const int e0 = (bi & 1) << 10;
  const int t  = threadIdx.x;
  if (t < HW_) al[t] = alpha[b*HW_ + t];
  __syncthreads();
  const float* base = enc + (size_t)b*HW_*ENC_ + e0 + t*4;
  float4 acc = {0.f, 0.f, 0.f, 0.f};
  #pragma unroll 4
  for (int s = 0; s < HW_; ++s) {
    const float a = al[s];
    const float4 v = *reinterpret_cast<const float4*>(base + (size_t)s*ENC_);
    acc.x = fmaf(a, v.x, acc.x);
    acc.y = fmaf(a, v.y, acc.y);
    acc.z = fmaf(a, v.z, acc.z);
    acc.w = fmaf(a, v.w, acc.w);
  }
  *reinterpret_cast<float4*>(&ctx[(size_t)b*ENC_ + e0 + t*4]) = acc;
}

// ---------------- launch
extern "C" void kernel_launch(void* const* d_in, const int* in_sizes, int n_in,
                              void* d_out, int out_size, void* d_ws, size_t ws_size,
                              hipStream_t stream) {
  const float* enc   = (const float*)d_in[0];
  const float* dec_h = (const float*)d_in[1];
  const float* Wenc  = (const float*)d_in[2];
  const float* benc  = (const float*)d_in[3];
  const float* Wdec  = (const float*)d_in[4];
  const float* bdec  = (const float*)d_in[5];
  const float* Wv    = (const float*)d_in[6];
  const float* bv    = (const float*)d_in[7];

  float* ctx   = (float*)d_out;                     // [512][2048]
  float* alpha = (float*)d_out + (size_t)B_*ENC_;   // [512][196]

  char* ws = (char*)d_ws;
  float*          attn2p   = (float*)ws;                          // 1.0 MB
  unsigned short* WencT    = (unsigned short*)(ws + (1u << 20));  // 2.0 MB
  float*          partials = (float*)(ws + 3u*(1u << 20));        // 1.6 MB  [M][4]

  hipLaunchKernelGGL(k_attn2,     dim3(B_),              dim3(256), 0, stream,
                     dec_h, Wdec, bdec, benc, attn2p);
  hipLaunchKernelGGL(k_transpose, dim3(ENC_/32, ATTN_/32), dim3(256), 0, stream,
                     Wenc, WencT);
  hipLaunchKernelGGL(k_gemm_logits, dim3(3136),          dim3(256), 0, stream,
                     enc, WencT, attn2p, Wv, partials);
  hipLaunchKernelGGL(k_softmax,   dim3(B_),              dim3(64),  0, stream,
                     partials, bv, alpha);
  hipLaunchKernelGGL(k_context,   dim3(1024),            dim3(256), 0, stream,
                     enc, alpha, ctx);
}

// Round 2
// 684.434 us; speedup vs baseline: 1.5035x; 1.5035x over previous
//
#include <hip/hip_runtime.h>
#include <hip/hip_bf16.h>
#include <cstdint>
#include <cstddef>

#define B_    512
#define HW_   196
#define ENC_  2048
#define DEC_  512
#define ATTN_ 512
#define M_    (B_*HW_)   // 100352

typedef __attribute__((ext_vector_type(8))) short short8;
typedef __attribute__((ext_vector_type(4))) float f32x4;

__device__ __forceinline__ unsigned short f2bf(float x) {
  union { float f; unsigned int u; } c; c.f = x;
  unsigned int u = c.u;
  return (unsigned short)((u + 0x7FFFu + ((u >> 16) & 1u)) >> 16);  // RNE
}

__device__ __forceinline__ void gload_lds16(const void* g, void* l) {
  __builtin_amdgcn_global_load_lds(
      (const __attribute__((address_space(1))) void*)g,
      (__attribute__((address_space(3))) void*)l, 16, 0, 0);
}

// ---------------- kernel 1: attn2p[b][a] = dec_h[b]·W_dec[:,a] + b_dec[a] + b_enc[a]
__global__ __launch_bounds__(256)
void k_attn2(const float* __restrict__ dec_h, const float* __restrict__ Wdec,
             const float* __restrict__ bdec, const float* __restrict__ benc,
             float* __restrict__ attn2p) {
  __shared__ float dh[DEC_];
  const int b = blockIdx.x;
  const int t = threadIdx.x;
  dh[t]       = dec_h[b*DEC_ + t];
  dh[t + 256] = dec_h[b*DEC_ + t + 256];
  __syncthreads();
  #pragma unroll
  for (int rep = 0; rep < 2; ++rep) {
    const int a = t + rep*256;
    float acc = bdec[a] + benc[a];
    #pragma unroll 8
    for (int k = 0; k < DEC_; ++k)
      acc = fmaf(dh[k], Wdec[(size_t)k*ATTN_ + a], acc);
    attn2p[(size_t)b*ATTN_ + a] = acc;
  }
}

// ---------------- kernel 2: W_encT[a][e] = bf16(W_enc[e][a])
__global__ __launch_bounds__(256)
void k_transpose(const float* __restrict__ Wenc, unsigned short* __restrict__ WencT) {
  __shared__ float tile[32][33];
  const int e0 = blockIdx.x * 32;
  const int a0 = blockIdx.y * 32;
  const int t  = threadIdx.x;
  const int li = t >> 5;
  const int lj = t & 31;
  #pragma unroll
  for (int rep = 0; rep < 4; ++rep) {
    const int i = li + rep*8;
    tile[i][lj] = Wenc[(size_t)(e0 + i)*ATTN_ + a0 + lj];
  }
  __syncthreads();
  #pragma unroll
  for (int rep = 0; rep < 4; ++rep) {
    const int ar = li + rep*8;
    WencT[(size_t)(a0 + ar)*ENC_ + e0 + lj] = f2bf(tile[lj][ar]);
  }
}

// ---------------- kernel 3: fused GEMM + bias + relu + dot(W_v) -> partial logits
// m97-class structure: BK=32, 2 barriers/K-step, 16 MFMA/K-step.
// B (bf16) staged via global_load_lds width-16, double-buffered (latency hidden).
// A (f32) reg-staged (16 floats/thread), f2bf convert, ds_write; padded LDA.
#define BM 128
#define BN 128
#define BK 32
#define LDA 40          // A LDS k-stride (elems): 80B rows, breaks pow2 banks
#define NT (ENC_/BK)    // 64

__global__ __launch_bounds__(256)
void k_gemm_logits(const float* __restrict__ enc,
                   const unsigned short* __restrict__ WencT,
                   const float* __restrict__ attn2p,
                   const float* __restrict__ Wv,
                   float* __restrict__ partials) {
  __shared__ unsigned short As[BM*LDA];     // 10 KB
  __shared__ unsigned short Bs[2][BN*BK];   // 2 x 8 KB (dbuf, linear for gload_lds)
  __shared__ float plog[BM][2];

  const int tid  = threadIdx.x;
  const int id   = blockIdx.x;
  const int xcd  = id & 7;
  const int rest = id >> 3;
  const int nb   = rest & 3;
  const int mblk = (rest >> 2) * 8 + xcd;   // 784 = 98*8, bijective; n-siblings share XCD
  const int r0 = mblk * BM;
  const int n0 = nb * BN;

  // A staging: 2 threads/row, 16 contiguous floats each
  const int arow  = tid >> 1;
  const int ahalf = (tid & 1) << 4;
  const float* aptr = enc + (size_t)(r0 + arow)*ENC_ + ahalf;

  const unsigned short* bbase = WencT + (size_t)n0*ENC_;

  // fragment coords
  const int w  = tid >> 6;
  const int l  = tid & 63;
  const int wm = w >> 1, wn = w & 1;
  const int lrow = l & 15;
  const int lk8  = (l >> 4) << 3;
  const int g4   = (l >> 4) << 2;

  f32x4 acc[4][4];
  #pragma unroll
  for (int mi = 0; mi < 4; ++mi)
    #pragma unroll
    for (int ni = 0; ni < 4; ++ni)
      acc[mi][ni] = (f32x4){0.f, 0.f, 0.f, 0.f};

  // prologue: A regs for kt=0; B tile 0 -> Bs[0]
  float4 ar[4];
  #pragma unroll
  for (int i = 0; i < 4; ++i) ar[i] = *reinterpret_cast<const float4*>(aptr + i*4);
  #pragma unroll
  for (int r = 0; r < 2; ++r) {
    const int idx = r*256 + tid;
    gload_lds16(bbase + (size_t)(idx >> 2)*ENC_ + (idx & 3)*8, &Bs[0][idx*8]);
  }

  for (int kt = 0; kt < NT; ++kt) {
    // ---- stage A tile kt into LDS (convert f32->bf16)
    {
      unsigned int pk[8];
      #pragma unroll
      for (int i = 0; i < 4; ++i) {
        pk[2*i]   = (unsigned)f2bf(ar[i].x) | ((unsigned)f2bf(ar[i].y) << 16);
        pk[2*i+1] = (unsigned)f2bf(ar[i].z) | ((unsigned)f2bf(ar[i].w) << 16);
      }
      uint4* da = reinterpret_cast<uint4*>(&As[arow*LDA + ahalf]);
      da[0] = make_uint4(pk[0], pk[1], pk[2], pk[3]);
      da[1] = make_uint4(pk[4], pk[5], pk[6], pk[7]);
    }
    __syncthreads();   // tile kt fully in LDS (A via ds_write, B via gload_lds)

    // ---- issue tile kt+1 loads (latency hides under the MFMA phase below)
    if (kt + 1 < NT) {
      const float* ap = aptr + (kt + 1)*BK;
      #pragma unroll
      for (int i = 0; i < 4; ++i) ar[i] = *reinterpret_cast<const float4*>(ap + i*4);
      const int k0n = (kt + 1)*BK;
      unsigned short* bdst = Bs[(kt + 1) & 1];
      #pragma unroll
      for (int r = 0; r < 2; ++r) {
        const int idx = r*256 + tid;
        gload_lds16(bbase + (size_t)(idx >> 2)*ENC_ + k0n + (idx & 3)*8, &bdst[idx*8]);
      }
    }

    // ---- compute tile kt
    const unsigned short* bsc = Bs[kt & 1];
    short8 aF[4], bF[4];
    #pragma unroll
    for (int mi = 0; mi < 4; ++mi)
      aF[mi] = *reinterpret_cast<const short8*>(&As[(wm*64 + mi*16 + lrow)*LDA + lk8]);
    #pragma unroll
    for (int ni = 0; ni < 4; ++ni)
      bF[ni] = *reinterpret_cast<const short8*>(&bsc[(wn*64 + ni*16 + lrow)*BK + lk8]);
    #pragma unroll
    for (int mi = 0; mi < 4; ++mi)
      #pragma unroll
      for (int ni = 0; ni < 4; ++ni)
        acc[mi][ni] = __builtin_amdgcn_mfma_f32_16x16x32_bf16(aF[mi], bF[ni], acc[mi][ni], 0, 0, 0);
    __syncthreads();   // MFMA reads done before next overwrite
  }

  // ---- epilogue: relu(acc + attn2p) · W_v, reduced over this block's 128 cols
  float wvv[4];
  #pragma unroll
  for (int ni = 0; ni < 4; ++ni) wvv[ni] = Wv[n0 + wn*64 + ni*16 + lrow];
  #pragma unroll
  for (int mi = 0; mi < 4; ++mi) {
    #pragma unroll
    for (int j = 0; j < 4; ++j) {
      const int row_local = wm*64 + mi*16 + g4 + j;
      const int r  = r0 + row_local;
      const int bb = r / HW_;
      const float* a2 = attn2p + (size_t)bb*ATTN_ + n0 + wn*64;
      float s = 0.f;
      #pragma unroll
      for (int ni = 0; ni < 4; ++ni) {
        float v = acc[mi][ni][j] + a2[ni*16 + lrow];
        v = fmaxf(v, 0.f);
        s = fmaf(v, wvv[ni], s);
      }
      s += __shfl_xor(s, 1);
      s += __shfl_xor(s, 2);
      s += __shfl_xor(s, 4);
      s += __shfl_xor(s, 8);
      if (lrow == 0) plog[row_local][wn] = s;
    }
  }
  __syncthreads();
  if (tid < BM)
    partials[(size_t)(r0 + tid)*4 + nb] = plog[tid][0] + plog[tid][1];
}

// ---------------- kernel 4: softmax over s (196) per b
__global__ __launch_bounds__(64)
void k_softmax(const float* __restrict__ partials, const float* __restrict__ bvp,
               float* __restrict__ alpha) {
  const int b = blockIdx.x;
  const int t = threadIdx.x;
  const float bv = bvp[0];
  float lg[4];
  #pragma unroll
  for (int i = 0; i < 4; ++i) {
    const int s = t + i*64;
    if (s < HW_) {
      const float4 p = *reinterpret_cast<const float4*>(&partials[(size_t)(b*HW_ + s)*4]);
      lg[i] = p.x + p.y + p.z + p.w + bv;
    } else lg[i] = -INFINITY;
  }
  float mx = fmaxf(fmaxf(lg[0], lg[1]), fmaxf(lg[2], lg[3]));
  #pragma unroll
  for (int off = 32; off; off >>= 1) mx = fmaxf(mx, __shfl_xor(mx, off));
  float sum = 0.f;
  #pragma unroll
  for (int i = 0; i < 4; ++i) { lg[i] = expf(lg[i] - mx); sum += lg[i]; }
  #pragma unroll
  for (int off = 32; off; off >>= 1) sum += __shfl_xor(sum, off);
  const float inv = 1.0f / sum;
  #pragma unroll
  for (int i = 0; i < 4; ++i) {
    const int s = t + i*64;
    if (s < HW_) alpha[b*HW_ + s] = lg[i] * inv;
  }
}

// ---------------- kernel 5: context[b][e] = sum_s alpha[b][s] * enc[b][s][e]
__global__ __launch_bounds__(256)
void k_context(const float* __restrict__ enc, const float* __restrict__ alpha,
               float* __restrict__ ctx) {
  __shared__ float al[HW_];
  const int bi = blockIdx.x;
  const int b  = bi >> 1;
  const int e0 = (bi & 1) << 10;
  const int t  = threadIdx.x;
  if (t < HW_) al[t] = alpha[b*HW_ + t];
  __syncthreads();
  const float* base = enc + (size_t)b*HW_*ENC_ + e0 + t*4;
  float4 acc = {0.f, 0.f, 0.f, 0.f};
  #pragma unroll 4
  for (int s = 0; s < HW_; ++s) {
    const float a = al[s];
    const float4 v = *reinterpret_cast<const float4*>(base + (size_t)s*ENC_);
    acc.x = fmaf(a, v.x, acc.x);
    acc.y = fmaf(a, v.y, acc.y);
    acc.z = fmaf(a, v.z, acc.z);
    acc.w = fmaf(a, v.w, acc.w);
  }
  *reinterpret_cast<float4*>(&ctx[(size_t)b*ENC_ + e0 + t*4]) = acc;
}

// ---------------- launch
extern "C" void kernel_launch(void* const* d_in, const int* in_sizes, int n_in,
                              void* d_out, int out_size, void* d_ws, size_t ws_size,
                              hipStream_t stream) {
  const float* enc   = (const float*)d_in[0];
  const float* dec_h = (const float*)d_in[1];
  const float* Wenc  = (const float*)d_in[2];
  const float* benc  = (const float*)d_in[3];
  const float* Wdec  = (const float*)d_in[4];
  const float* bdec  = (const float*)d_in[5];
  const float* Wv    = (const float*)d_in[6];
  const float* bv    = (const float*)d_in[7];

  float* ctx   = (float*)d_out;                     // [512][2048]
  float* alpha = (float*)d_out + (size_t)B_*ENC_;   // [512][196]

  char* ws = (char*)d_ws;
  float*          attn2p   = (float*)ws;                          // 1.0 MB
  unsigned short* WencT    = (unsigned short*)(ws + (1u << 20));  // 2.0 MB
  float*          partials = (float*)(ws + 3u*(1u << 20));        // 1.6 MB  [M][4]

  hipLaunchKernelGGL(k_attn2,     dim3(B_),               dim3(256), 0, stream,
                     dec_h, Wdec, bdec, benc, attn2p);
  hipLaunchKernelGGL(k_transpose, dim3(ENC_/32, ATTN_/32), dim3(256), 0, stream,
                     Wenc, WencT);
  hipLaunchKernelGGL(k_gemm_logits, dim3(3136),           dim3(256), 0, stream,
                     enc, WencT, attn2p, Wv, partials);
  hipLaunchKernelGGL(k_softmax,   dim3(B_),               dim3(64),  0, stream,
                     partials, bv, alpha);
  hipLaunchKernelGGL(k_context,   dim3(1024),             dim3(256), 0, stream,
                     enc, alpha, ctx);
}

// Round 3
// 673.318 us; speedup vs baseline: 1.5284x; 1.0165x over previous
//
#include <hip/hip_runtime.h>
#include <hip/hip_bf16.h>
#include <cstdint>
#include <cstddef>

#define B_    512
#define HW_   196
#define ENC_  2048
#define DEC_  512
#define ATTN_ 512
#define M_    (B_*HW_)   // 100352

typedef __attribute__((ext_vector_type(8))) short short8;
typedef __attribute__((ext_vector_type(4))) float f32x4;

// hardware RNE f32->bf16 (compiler emits v_cvt_pk_bf16_f32 on gfx950; per
// T12/m240 the scalar-cast path beats hand-written inline asm)
__device__ __forceinline__ unsigned short f2bf(float x) {
  __bf16 b = (__bf16)x;
  return __builtin_bit_cast(unsigned short, b);
}
__device__ __forceinline__ unsigned int cvt2(float x, float y) {
  return (unsigned)f2bf(x) | ((unsigned)f2bf(y) << 16);
}

__device__ __forceinline__ void gload_lds16(const void* g, void* l) {
  __builtin_amdgcn_global_load_lds(
      (const __attribute__((address_space(1))) void*)g,
      (__attribute__((address_space(3))) void*)l, 16, 0, 0);
}

// inverse of p = c ^ ((c>>2)&7)  (16B-chunk swizzle for the B tile)
__device__ __forceinline__ int invswz8(int p) {
  const int b2 = ((p >> 2) ^ (p >> 4)) & 1;
  const int b1 = ((p >> 1) ^ (p >> 3)) & 1;
  const int b0 = (p ^ (p >> 2) ^ (p >> 4)) & 1;
  return (p & ~7) | (b2 << 2) | (b1 << 1) | b0;
}

// ---------------- kernel 1: attn2p[b][a] = dec_h[b]·W_dec[:,a] + b_dec[a] + b_enc[a]
__global__ __launch_bounds__(256)
void k_attn2(const float* __restrict__ dec_h, const float* __restrict__ Wdec,
             const float* __restrict__ bdec, const float* __restrict__ benc,
             float* __restrict__ attn2p) {
  __shared__ float dh[DEC_];
  const int b = blockIdx.x;
  const int t = threadIdx.x;
  dh[t]       = dec_h[b*DEC_ + t];
  dh[t + 256] = dec_h[b*DEC_ + t + 256];
  __syncthreads();
  #pragma unroll
  for (int rep = 0; rep < 2; ++rep) {
    const int a = t + rep*256;
    float acc = bdec[a] + benc[a];
    #pragma unroll 8
    for (int k = 0; k < DEC_; ++k)
      acc = fmaf(dh[k], Wdec[(size_t)k*ATTN_ + a], acc);
    attn2p[(size_t)b*ATTN_ + a] = acc;
  }
}

// ---------------- kernel 2: W_encT[a][e] = bf16(W_enc[e][a])
__global__ __launch_bounds__(256)
void k_transpose(const float* __restrict__ Wenc, unsigned short* __restrict__ WencT) {
  __shared__ float tile[32][33];
  const int e0 = blockIdx.x * 32;
  const int a0 = blockIdx.y * 32;
  const int t  = threadIdx.x;
  const int li = t >> 5;
  const int lj = t & 31;
  #pragma unroll
  for (int rep = 0; rep < 4; ++rep) {
    const int i = li + rep*8;
    tile[i][lj] = Wenc[(size_t)(e0 + i)*ATTN_ + a0 + lj];
  }
  __syncthreads();
  #pragma unroll
  for (int rep = 0; rep < 4; ++rep) {
    const int ar = li + rep*8;
    WencT[(size_t)(a0 + ar)*ENC_ + e0 + lj] = f2bf(tile[lj][ar]);
  }
}

// ---------------- kernel 3: fused GEMM + bias + relu + dot(W_v) -> partial logits
// m97-class: BK=32, 2 barriers/K-step, 16 MFMA/K-step.
// B: global_load_lds w16, double-buffered, chunk-swizzled (source-side XOR,
//    linear LDS dest — m173 pattern) for conflict-free ds_read_b128.
// A: f32 reg-staged (T14 split), hw cvt_pk f32->bf16, LDA=40 pad.
#define BM 128
#define BN 128
#define BK 32
#define LDA 40
#define NT (ENC_/BK)    // 64

__global__ __launch_bounds__(256)
void k_gemm_logits(const float* __restrict__ enc,
                   const unsigned short* __restrict__ WencT,
                   const float* __restrict__ attn2p,
                   const float* __restrict__ Wv,
                   float* __restrict__ partials) {
  __shared__ unsigned short As[BM*LDA];     // 10 KB
  __shared__ unsigned short Bs[2][BN*BK];   // 2 x 8 KB
  __shared__ float plog[BM][2];

  const int tid  = threadIdx.x;
  const int id   = blockIdx.x;
  const int xcd  = id & 7;
  const int rest = id >> 3;
  const int nb   = rest & 3;
  const int mblk = (rest >> 2) * 8 + xcd;   // 784 = 98*8, bijective; n-siblings share XCD
  const int r0 = mblk * BM;
  const int n0 = nb * BN;

  const int arow  = tid >> 1;
  const int ahalf = (tid & 1) << 4;
  const float* aptr = enc + (size_t)(r0 + arow)*ENC_ + ahalf;

  const unsigned short* bbase = WencT + (size_t)n0*ENC_;

  const int w  = tid >> 6;
  const int l  = tid & 63;
  const int wm = w >> 1, wn = w & 1;
  const int lrow = l & 15;
  const int kg   = l >> 4;        // k-group 0..3
  const int lk8  = kg << 3;
  const int g4   = kg << 2;

  f32x4 acc[4][4];
  #pragma unroll
  for (int mi = 0; mi < 4; ++mi)
    #pragma unroll
    for (int ni = 0; ni < 4; ++ni)
      acc[mi][ni] = (f32x4){0.f, 0.f, 0.f, 0.f};

  // prologue: A regs for kt=0; B tile 0 -> Bs[0] (swizzled source)
  float4 ar[4];
  #pragma unroll
  for (int i = 0; i < 4; ++i) ar[i] = *reinterpret_cast<const float4*>(aptr + i*4);
  #pragma unroll
  for (int r = 0; r < 2; ++r) {
    const int p = r*256 + tid;
    const int c = invswz8(p);
    gload_lds16(bbase + (size_t)(c >> 2)*ENC_ + (c & 3)*8, &Bs[0][p*8]);
  }

  for (int kt = 0; kt < NT; ++kt) {
    // ---- stage A tile kt into LDS (hw cvt f32->bf16)
    {
      unsigned int pk[8];
      #pragma unroll
      for (int i = 0; i < 4; ++i) {
        pk[2*i]   = cvt2(ar[i].x, ar[i].y);
        pk[2*i+1] = cvt2(ar[i].z, ar[i].w);
      }
      uint4* da = reinterpret_cast<uint4*>(&As[arow*LDA + ahalf]);
      da[0] = make_uint4(pk[0], pk[1], pk[2], pk[3]);
      da[1] = make_uint4(pk[4], pk[5], pk[6], pk[7]);
    }
    __syncthreads();   // tile kt fully in LDS

    // ---- issue tile kt+1 loads (hide under MFMA below)
    if (kt + 1 < NT) {
      const float* ap = aptr + (kt + 1)*BK;
      #pragma unroll
      for (int i = 0; i < 4; ++i) ar[i] = *reinterpret_cast<const float4*>(ap + i*4);
      const int k0n = (kt + 1)*BK;
      unsigned short* bdst = Bs[(kt + 1) & 1];
      #pragma unroll
      for (int r = 0; r < 2; ++r) {
        const int p = r*256 + tid;
        const int c = invswz8(p);
        gload_lds16(bbase + (size_t)(c >> 2)*ENC_ + k0n + (c & 3)*8, &bdst[p*8]);
      }
    }

    // ---- compute tile kt
    const unsigned short* bsc = Bs[kt & 1];
    short8 aF[4], bF[4];
    #pragma unroll
    for (int mi = 0; mi < 4; ++mi)
      aF[mi] = *reinterpret_cast<const short8*>(&As[(wm*64 + mi*16 + lrow)*LDA + lk8]);
    #pragma unroll
    for (int ni = 0; ni < 4; ++ni) {
      const int cr = ((wn*64 + ni*16 + lrow) << 2) + kg;
      const int pr = cr ^ ((cr >> 2) & 7);
      bF[ni] = *reinterpret_cast<const short8*>(&bsc[pr << 3]);
    }
    #pragma unroll
    for (int mi = 0; mi < 4; ++mi)
      #pragma unroll
      for (int ni = 0; ni < 4; ++ni)
        acc[mi][ni] = __builtin_amdgcn_mfma_f32_16x16x32_bf16(aF[mi], bF[ni], acc[mi][ni], 0, 0, 0);
    __syncthreads();   // MFMA reads done before next overwrite
  }

  // ---- epilogue: relu(acc + attn2p) · W_v, reduced over this block's 128 cols
  float wvv[4];
  #pragma unroll
  for (int ni = 0; ni < 4; ++ni) wvv[ni] = Wv[n0 + wn*64 + ni*16 + lrow];
  #pragma unroll
  for (int mi = 0; mi < 4; ++mi) {
    #pragma unroll
    for (int j = 0; j < 4; ++j) {
      const int row_local = wm*64 + mi*16 + g4 + j;
      const int r  = r0 + row_local;
      const int bb = r / HW_;
      const float* a2 = attn2p + (size_t)bb*ATTN_ + n0 + wn*64;
      float s = 0.f;
      #pragma unroll
      for (int ni = 0; ni < 4; ++ni) {
        float v = acc[mi][ni][j] + a2[ni*16 + lrow];
        v = fmaxf(v, 0.f);
        s = fmaf(v, wvv[ni], s);
      }
      s += __shfl_xor(s, 1);
      s += __shfl_xor(s, 2);
      s += __shfl_xor(s, 4);
      s += __shfl_xor(s, 8);
      if (lrow == 0) plog[row_local][wn] = s;
    }
  }
  __syncthreads();
  if (tid < BM)
    partials[(size_t)(r0 + tid)*4 + nb] = plog[tid][0] + plog[tid][1];
}

// ---------------- kernel 4: softmax over s (196) per b
__global__ __launch_bounds__(64)
void k_softmax(const float* __restrict__ partials, const float* __restrict__ bvp,
               float* __restrict__ alpha) {
  const int b = blockIdx.x;
  const int t = threadIdx.x;
  const float bv = bvp[0];
  float lg[4];
  #pragma unroll
  for (int i = 0; i < 4; ++i) {
    const int s = t + i*64;
    if (s < HW_) {
      const float4 p = *reinterpret_cast<const float4*>(&partials[(size_t)(b*HW_ + s)*4]);
      lg[i] = p.x + p.y + p.z + p.w + bv;
    } else lg[i] = -INFINITY;
  }
  float mx = fmaxf(fmaxf(lg[0], lg[1]), fmaxf(lg[2], lg[3]));
  #pragma unroll
  for (int off = 32; off; off >>= 1) mx = fmaxf(mx, __shfl_xor(mx, off));
  float sum = 0.f;
  #pragma unroll
  for (int i = 0; i < 4; ++i) { lg[i] = expf(lg[i] - mx); sum += lg[i]; }
  #pragma unroll
  for (int off = 32; off; off >>= 1) sum += __shfl_xor(sum, off);
  const float inv = 1.0f / sum;
  #pragma unroll
  for (int i = 0; i < 4; ++i) {
    const int s = t + i*64;
    if (s < HW_) alpha[b*HW_ + s] = lg[i] * inv;
  }
}

// ---------------- kernel 5: context[b][e] = sum_s alpha[b][s] * enc[b][s][e]
__global__ __launch_bounds__(256)
void k_context(const float* __restrict__ enc, const float* __restrict__ alpha,
               float* __restrict__ ctx) {
  __shared__ float al[HW_];
  const int bi = blockIdx.x;
  const int b  = bi >> 1;
  const int e0 = (bi & 1) << 10;
  const int t  = threadIdx.x;
  if (t < HW_) al[t] = alpha[b*HW_ + t];
  __syncthreads();
  const float* base = enc + (size_t)b*HW_*ENC_ + e0 + t*4;
  float4 acc = {0.f, 0.f, 0.f, 0.f};
  #pragma unroll 4
  for (int s = 0; s < HW_; ++s) {
    const float a = al[s];
    const float4 v = *reinterpret_cast<const float4*>(base + (size_t)s*ENC_);
    acc.x = fmaf(a, v.x, acc.x);
    acc.y = fmaf(a, v.y, acc.y);
    acc.z = fmaf(a, v.z, acc.z);
    acc.w = fmaf(a, v.w, acc.w);
  }
  *reinterpret_cast<float4*>(&ctx[(size_t)b*ENC_ + e0 + t*4]) = acc;
}

// ---------------- launch
extern "C" void kernel_launch(void* const* d_in, const int* in_sizes, int n_in,
                              void* d_out, int out_size, void* d_ws, size_t ws_size,
                              hipStream_t stream) {
  const float* enc   = (const float*)d_in[0];
  const float* dec_h = (const float*)d_in[1];
  const float* Wenc  = (const float*)d_in[2];
  const float* benc  = (const float*)d_in[3];
  const float* Wdec  = (const float*)d_in[4];
  const float* bdec  = (const float*)d_in[5];
  const float* Wv    = (const float*)d_in[6];
  const float* bv    = (const float*)d_in[7];

  float* ctx   = (float*)d_out;                     // [512][2048]
  float* alpha = (float*)d_out + (size_t)B_*ENC_;   // [512][196]

  char* ws = (char*)d_ws;
  float*          attn2p   = (float*)ws;                          // 1.0 MB
  unsigned short* WencT    = (unsigned short*)(ws + (1u << 20));  // 2.0 MB
  float*          partials = (float*)(ws + 3u*(1u << 20));        // 1.6 MB  [M][4]

  hipLaunchKernelGGL(k_attn2,     dim3(B_),               dim3(256), 0, stream,
                     dec_h, Wdec, bdec, benc, attn2p);
  hipLaunchKernelGGL(k_transpose, dim3(ENC_/32, ATTN_/32), dim3(256), 0, stream,
                     Wenc, WencT);
  hipLaunchKernelGGL(k_gemm_logits, dim3(3136),           dim3(256), 0, stream,
                     enc, WencT, attn2p, Wv, partials);
  hipLaunchKernelGGL(k_softmax,   dim3(B_),               dim3(64),  0, stream,
                     partials, bv, alpha);
  hipLaunchKernelGGL(k_context,   dim3(1024),             dim3(256), 0, stream,
                     enc, alpha, ctx);
}